// Round 5
// baseline (527.698 us; speedup 1.0000x reference)
//
#include <hip/hip_runtime.h>
#include <hip/hip_bf16.h>
#include <cstdint>

// Problem constants
#define IMGE    384
#define XROWS   51              // LDS rows (need up to row 50 = 16*2+15+3)
#define XROWB   (XROWS * 640)   // 32640 bytes (320 bf16 cols, 640 B/row)
#define BLOB_OFF 256

using bf16x8 = short  __attribute__((ext_vector_type(8)));
using f32x4  = float  __attribute__((ext_vector_type(4)));

__device__ __forceinline__ unsigned int f2bf(float f) {
  unsigned int u = __builtin_bit_cast(unsigned int, f);
  u += 0x7FFFu + ((u >> 16) & 1u);          // round-to-nearest-even
  return u >> 16;
}

#define MF(a, b, c) __builtin_amdgcn_mfma_f32_16x16x32_bf16(a, b, c, 0, 0, 0)

// ---------------------------------------------------------------------------
// Prep: repack conv weights (fp32, [256][1][k][300]) into bf16 fragment-order
// blob: byte = ((kappa*768 + F)*32 + e')*2, kappa = j*10+kk, e = kk*32+e'.
// Zero-pad j >= k and e >= 300. One wave-load in the main kernel = 1KB contig.
// ---------------------------------------------------------------------------
__global__ __launch_bounds__(256) void prep_weights(
    const float* __restrict__ w2, const float* __restrict__ w3,
    const float* __restrict__ w4, unsigned short* __restrict__ blob)
{
  int kappa = blockIdx.x;                       // 0..39
  int fq = blockIdx.y * 256 + threadIdx.x;      // F*4 + q, 0..3071
  int F = fq >> 2;
  int q = fq & 3;
  int j = kappa / 10, kk = kappa - 10 * j;
  int ch = F >> 8, f = F & 255;
  int k = ch + 2;
  const float* w = (ch == 0) ? w2 : (ch == 1 ? w3 : w4);

  bf16x8 pv;
  if (j < k) {
    const float* src = w + (size_t)(f * k + j) * 300;
    #pragma unroll
    for (int i = 0; i < 8; i++) {
      int e = kk * 32 + q * 8 + i;
      pv[i] = (e < 300) ? (short)f2bf(src[e]) : (short)0;
    }
  } else {
    #pragma unroll
    for (int i = 0; i < 8; i++) pv[i] = 0;
  }
  unsigned short* dst = blob + (size_t)(kappa * 768 + F) * 32 + q * 8;
  *(bf16x8*)dst = pv;
}

// ---------------------------------------------------------------------------
// GEMM inner loop: 4 N-tiles with compile-time tap counts K0..K3.
// Fully unrolled (j,kk) steps; A (LDS) and B (L2 blob) register double-buffer
// one step ahead; setprio(1) around each MFMA cluster.
// ---------------------------------------------------------------------------
template<int K0, int K1, int K2, int K3>
__device__ __forceinline__ void gemm4(
    const char* Xs, const char* bb0, const char* bb1,
    const char* bb2, const char* bb3,
    int l15, int hi, f32x4 (&acc)[4][3])
{
  constexpr int KA = K0 > K1 ? K0 : K1;
  constexpr int KB = K2 > K3 ? K2 : K3;
  constexpr int KM = KA > KB ? KA : KB;
  constexpr int T  = KM * 10;

  bf16x8 A0, A1, A2, B0, B1, B2, B3;
  bf16x8 nA0, nA1, nA2, nB0, nB1, nB2, nB3;

#define LOADA(J, KK, D0, D1, D2) {                                     \
    int hx = (hi * 16) ^ ((((l15) + (J)) & 7) << 4);                   \
    int cc = ((KK) * 64) ^ hx;                                         \
    D0 = *(const bf16x8*)(Xs + ((0 * 16 + l15 + (J)) * 640 + cc));     \
    D1 = *(const bf16x8*)(Xs + ((1 * 16 + l15 + (J)) * 640 + cc));     \
    D2 = *(const bf16x8*)(Xs + ((2 * 16 + l15 + (J)) * 640 + cc)); }

#define LOADB(J, KK, D0, D1, D2, D3) {                                 \
    const int ko = ((J) * 10 + (KK)) * 49152;                          \
    if ((J) < K0) D0 = *(const bf16x8*)(bb0 + ko);                     \
    if ((J) < K1) D1 = *(const bf16x8*)(bb1 + ko);                     \
    if ((J) < K2) D2 = *(const bf16x8*)(bb2 + ko);                     \
    if ((J) < K3) D3 = *(const bf16x8*)(bb3 + ko); }

  #pragma unroll
  for (int t = 0; t < T; ++t) {
    const int j  = t / 10, kk = t - 10 * (t / 10);
    if (t == 0) { LOADA(j, kk, A0, A1, A2) LOADB(j, kk, B0, B1, B2, B3) }
    if (t + 1 < T) {
      const int t2 = t + 1;
      const int j2 = t2 / 10, kk2 = t2 - 10 * (t2 / 10);
      LOADA(j2, kk2, nA0, nA1, nA2) LOADB(j2, kk2, nB0, nB1, nB2, nB3)
    }
    __builtin_amdgcn_s_setprio(1);
    if (j < K0) { acc[0][0] = MF(A0, B0, acc[0][0]); acc[0][1] = MF(A1, B0, acc[0][1]); acc[0][2] = MF(A2, B0, acc[0][2]); }
    if (j < K1) { acc[1][0] = MF(A0, B1, acc[1][0]); acc[1][1] = MF(A1, B1, acc[1][1]); acc[1][2] = MF(A2, B1, acc[1][2]); }
    if (j < K2) { acc[2][0] = MF(A0, B2, acc[2][0]); acc[2][1] = MF(A1, B2, acc[2][1]); acc[2][2] = MF(A2, B2, acc[2][2]); }
    if (j < K3) { acc[3][0] = MF(A0, B3, acc[3][0]); acc[3][1] = MF(A1, B3, acc[3][1]); acc[3][2] = MF(A2, B3, acc[3][2]); }
    __builtin_amdgcn_s_setprio(0);
    if (t + 1 < T) {
      A0 = nA0; A1 = nA1; A2 = nA2;
      B0 = nB0; B1 = nB1; B2 = nB2; B3 = nB3;
    }
  }
#undef LOADA
#undef LOADB
}

// ---------------------------------------------------------------------------
// Main: one block = 768 threads (12 waves), ONE sentence. Each wave owns 4
// N-tiles, channel-balanced: wv<8 -> {ch0,ch0,ch2,ch2}, wv>=8 -> {ch1 x4}.
// acc = 4n x 3m x f32x4 = 48 regs -> 3 waves/SIMD (37.5% occ). A and B both
// register-double-buffered one (j,kk)-step ahead.
// ---------------------------------------------------------------------------
__global__ __launch_bounds__(768, 3) void main_conv(
    const int*  __restrict__ sb,   const float* __restrict__ W,
    const float* __restrict__ b2,  const float* __restrict__ b3,
    const float* __restrict__ b4,  const unsigned short* __restrict__ blob,
    float* __restrict__ out, float* __restrict__ nrm)
{
  __shared__ __align__(128) char X[XROWB];      // 32640 B
  __shared__ float wss[12];
  const int tid = threadIdx.x;
  const int wv  = tid >> 6;                     // 0..11
  const int l   = tid & 63;
  const int l15 = l & 15;
  const int hi  = l >> 4;
  const int Sid = blockIdx.x;                   // sentence id 0..4095

  // zero LDS (covers e in [300,320) pads and rows 40..50)
  for (int off = tid * 16; off < XROWB; off += 768 * 16)
    *(f32x4*)(X + off) = f32x4{0.f, 0.f, 0.f, 0.f};
  __syncthreads();

  // gather embeddings: 40 rows x 75 float4 chunks
  for (int idx = tid; idx < 3000; idx += 768) {
    int r  = idx / 75;
    int c4 = idx - r * 75;
    int tok = sb[Sid * 40 + r];
    float4 wvv = *(const float4*)(W + (size_t)tok * 300 + c4 * 4);
    uint2 pk;
    pk.x = f2bf(wvv.x) | (f2bf(wvv.y) << 16);
    pk.y = f2bf(wvv.z) | (f2bf(wvv.w) << 16);
    int off = r * 640 + ((c4 * 8) ^ ((r & 7) << 4));
    *(uint2*)(X + off) = pk;
  }
  __syncthreads();

  f32x4 acc[4][3];
  #pragma unroll
  for (int n = 0; n < 4; n++)
    #pragma unroll
    for (int m = 0; m < 3; m++)
      acc[n][m] = f32x4{0.f, 0.f, 0.f, 0.f};

  // tile assignment (wave-uniform)
  int Fb[4], chn[4];
  if (wv < 8) {
    Fb[0] = wv * 32;       Fb[1] = wv * 32 + 16;
    Fb[2] = 512 + wv * 32; Fb[3] = 512 + wv * 32 + 16;
    chn[0] = 0; chn[1] = 0; chn[2] = 2; chn[3] = 2;
  } else {
    int u = wv - 8;
    Fb[0] = 256 + u * 64;      Fb[1] = 256 + u * 64 + 16;
    Fb[2] = 256 + u * 64 + 32; Fb[3] = 256 + u * 64 + 48;
    chn[0] = 1; chn[1] = 1; chn[2] = 1; chn[3] = 1;
  }

  const int laneB = l15 * 64 + hi * 16;
  const char* blobc = (const char*)blob + laneB;

  if (wv < 8)
    gemm4<2, 2, 4, 4>(X, blobc + Fb[0] * 64, blobc + Fb[1] * 64,
                         blobc + Fb[2] * 64, blobc + Fb[3] * 64, l15, hi, acc);
  else
    gemm4<3, 3, 3, 3>(X, blobc + Fb[0] * 64, blobc + Fb[1] * 64,
                         blobc + Fb[2] * 64, blobc + Fb[3] * 64, l15, hi, acc);

  // epilogue: maxpool(valid p) -> +bias -> relu -> norm SS + patch scatter
  float ss = 0.f;
  const int b = Sid >> 9, c = Sid & 511;
  #pragma unroll
  for (int n = 0; n < 4; n++) {
    int ch = chn[n];
    int F  = Fb[n] + l15;
    int plim = 39 - ch;                          // valid p: p < 41-k, k=ch+2
    float vmax = -1e30f;
    #pragma unroll
    for (int m = 0; m < 3; m++) {
      #pragma unroll
      for (int rg = 0; rg < 4; rg++) {
        int p = 16 * m + 4 * hi + rg;
        if (p < plim) vmax = fmaxf(vmax, acc[n][m][rg]);
      }
    }
    vmax = fmaxf(vmax, __shfl_xor(vmax, 16, 64));
    vmax = fmaxf(vmax, __shfl_xor(vmax, 32, 64));
    const float* bias = (ch == 0) ? b2 : (ch == 1 ? b3 : b4);
    float val = fmaxf(vmax + bias[F & 255], 0.f);
    if (hi == 0) {
      float mult = (c == 511) ? 65.f : 1.f;
      ss += mult * val * val;                    // norm uses pre-clip img
      float st = fminf(val, 1.f);                // clamp to [0,1]; val>=0
      int fi = F & 255;
      int pi = fi >> 4, pj = fi & 15;
      if (c < 511) {
        int pr = c / 24, pc = c - pr * 24;
        out[((size_t)(b * 3 + ch) * IMGE + pr * 16 + pi) * IMGE + pc * 16 + pj] = st;
      } else {
        for (int pidx = 511; pidx < 576; pidx++) {
          int pr = pidx / 24, pc = pidx - pr * 24;
          out[((size_t)(b * 3 + ch) * IMGE + pr * 16 + pi) * IMGE + pc * 16 + pj] = st;
        }
      }
    }
  }
  #pragma unroll
  for (int off = 32; off; off >>= 1) ss += __shfl_xor(ss, off, 64);
  if (l == 0) wss[wv] = ss;
  __syncthreads();
  if (tid == 0) {
    float tt = 0.f;
    #pragma unroll
    for (int i = 0; i < 12; i++) tt += wss[i];
    atomicAdd(nrm, tt);
  }
}

__global__ void finalize(const float* __restrict__ nrm, float* __restrict__ out) {
  if (threadIdx.x == 0) out[3538944] = sqrtf(nrm[0]) * 0.125f;
}

extern "C" void kernel_launch(void* const* d_in, const int* in_sizes, int n_in,
                              void* d_out, int out_size, void* d_ws, size_t ws_size,
                              hipStream_t stream)
{
  const int*   sb = (const int*)d_in[0];
  const float* W  = (const float*)d_in[1];
  const float* w2 = (const float*)d_in[2];
  const float* b2 = (const float*)d_in[3];
  const float* w3 = (const float*)d_in[4];
  const float* b3 = (const float*)d_in[5];
  const float* w4 = (const float*)d_in[6];
  const float* b4 = (const float*)d_in[7];
  float* out = (float*)d_out;
  float* nrm = (float*)d_ws;
  unsigned short* blob = (unsigned short*)((char*)d_ws + BLOB_OFF);

  hipMemsetAsync(d_ws, 0, 8, stream);                       // norm accumulator
  prep_weights<<<dim3(40, 12), 256, 0, stream>>>(w2, w3, w4, blob);
  main_conv<<<4096, 768, 0, stream>>>(sb, W, b2, b3, b4, blob, out, nrm);
  finalize<<<1, 64, 0, stream>>>(nrm, out);
}